// Round 8
// baseline (105.226 us; speedup 1.0000x reference)
//
#include <hip/hip_runtime.h>

// MEASUREMENT ROUND: same mux kernel as round 7, launched 3x (idempotent -> 
// correctness-neutral). dur_us(3x) - dur_us(1x from round 7) = 2 * kernel_time,
// disambiguating the reset-dominated timing window. Revert to 1x next round.
//
// Spherical harmonics Y_l^m, l = 0..3, complex (re,im), packed [B,N,N,16,2] f32.
// 8 lanes per point (redundant closed-form compute), each lane stores ONE
// float4 = quad (gt&7) of point (gt>>3) via branchless 7-select mux.
// out4[gt] is lane-consecutive -> every wave-store is 1 KiB contiguous.

constexpr int TPB = 256;

__device__ __forceinline__ float4 sel4(bool c, const float4& a, const float4& b) {
    return make_float4(c ? a.x : b.x, c ? a.y : b.y, c ? a.z : b.z, c ? a.w : b.w);
}

__global__ __launch_bounds__(256) void spharm16_kernel(const float* __restrict__ X,
                                                       float4* __restrict__ out4,
                                                       int nf4) {
    const int gt = blockIdx.x * TPB + threadIdx.x;   // global float4 index
    if (gt >= nf4) return;
    const int p = gt >> 3;                           // point (8 lanes share)
    const int q = gt & 7;                            // quad within point

    const float x = X[3 * p + 0];
    const float y = X[3 * p + 1];
    const float z = X[3 * p + 2];

    const float r2   = x * x + y * y + z * z;
    const float rinv = rsqrtf(r2);
    const float ct   = z * rinv;
    const float ct2  = ct * ct;
    const float st2  = fmaxf(1.0f - ct2, 0.0f);
    const float st   = sqrtf(st2);

    const float rho2 = x * x + y * y;
    const float pinv = rsqrtf(rho2);
    const bool  okp  = rho2 > 0.0f;
    const float c1   = okp ? x * pinv : 1.0f;
    const float s1   = okp ? y * pinv : 0.0f;
    const float c2   = c1 * c1 - s1 * s1;
    const float s2   = 2.0f * c1 * s1;
    const float c3   = c2 * c1 - s2 * s1;
    const float s3   = s2 * c1 + c2 * s1;

    const float S1  = 0.34549414947133547f * st;
    const float B10 = 0.48860251190291992f * ct;
    const float B20 = 0.63078313050504031f * (1.5f * ct2 - 0.5f);
    const float T21 = 0.77254840404637910f * ct * st;
    const float B22 = 0.38627420202318955f * st2;
    const float B30 = 0.74635266518023080f * ct * (2.5f * ct2 - 1.5f);
    const float B31 = 0.32318018411248776f * st * (1.0f - 5.0f * ct2);
    const float B32 = 1.02198547643188850f * ct * st2;
    const float T33 = 0.41722382363278404f * st2 * st;

    const float S1c1  = S1  * c1, S1s1  = S1  * s1;
    const float T21c1 = T21 * c1, T21s1 = T21 * s1;
    const float B22c2 = B22 * c2, B22s2 = B22 * s2;
    const float B31c1 = B31 * c1, B31s1 = B31 * s1;
    const float B32c2 = B32 * c2, B32s2 = B32 * s2;
    const float T33c3 = T33 * c3, T33s3 = T33 * s3;

    const float4 q0 = make_float4(0.28209479177387814f, 0.0f,  S1c1, -S1s1);
    const float4 q1 = make_float4(B10,    0.0f,  -S1c1,  -S1s1);
    const float4 q2 = make_float4(B22c2, -B22s2,  T21c1, -T21s1);
    const float4 q3 = make_float4(B20,    0.0f,  -T21c1, -T21s1);
    const float4 q4 = make_float4(B22c2,  B22s2,  T33c3, -T33s3);
    const float4 q5 = make_float4(B32c2, -B32s2, -B31c1,  B31s1);
    const float4 q6 = make_float4(B30,    0.0f,   B31c1,  B31s1);
    const float4 q7 = make_float4(B32c2,  B32s2, -T33c3, -T33s3);

    const bool b0 = (q & 1) != 0;
    const bool b1 = (q & 2) != 0;
    const bool b2 = (q & 4) != 0;
    const float4 m01 = sel4(b0, q1, q0);
    const float4 m23 = sel4(b0, q3, q2);
    const float4 m45 = sel4(b0, q5, q4);
    const float4 m67 = sel4(b0, q7, q6);
    const float4 n0  = sel4(b1, m23, m01);
    const float4 n1  = sel4(b1, m67, m45);
    const float4 res = sel4(b2, n1, n0);

    out4[gt] = res;
}

extern "C" void kernel_launch(void* const* d_in, const int* in_sizes, int n_in,
                              void* d_out, int out_size, void* d_ws, size_t ws_size,
                              hipStream_t stream) {
    const float* X = (const float*)d_in[0];
    float4* out4 = (float4*)d_out;
    const int npts = in_sizes[0] / 3;          // 524288
    const int nf4  = npts * 8;
    const int blocks = (nf4 + TPB - 1) / TPB;  // 16384
    // 3 identical launches: dur_us_delta vs round 7 = 2 * kernel_time.
    spharm16_kernel<<<blocks, TPB, 0, stream>>>(X, out4, nf4);
    spharm16_kernel<<<blocks, TPB, 0, stream>>>(X, out4, nf4);
    spharm16_kernel<<<blocks, TPB, 0, stream>>>(X, out4, nf4);
}

// Round 12
// 81.825 us; speedup vs baseline: 1.2860x; 1.2860x over previous
//
#include <hip/hip_runtime.h>

// Spherical harmonics Y_l^m, l = 0..3, complex (re,im), packed [B,N,N,16,2] f32.
// 8 lanes per point (redundant closed-form compute); each lane produces ONE
// float4 (quad = idx&7 of point = idx>>3) via branchless 7-select mux.
// Grid-stride x8 (2048 blocks) + nontemporal dwordx4 stores (skip L2
// write-allocate for the 64 MiB write-once stream). Native ext_vector f4
// because __builtin_nontemporal_store rejects HIP_vector_type float4.
// Measured (r7/r8 1x-vs-3x probe): kernel ~13.7 us inside a fixed ~64 us
// harness-reset window; write floor ~11.2 us.

constexpr int TPB = 256;
constexpr int K   = 8;   // float4s per thread

using f4 = __attribute__((ext_vector_type(4))) float;  // native vector: nt-store OK

__device__ __forceinline__ f4 mkf4(float a, float b, float c, float d) {
    f4 v; v.x = a; v.y = b; v.z = c; v.w = d; return v;
}

__device__ __forceinline__ f4 sel4(bool c, f4 a, f4 b) {
    f4 r;
    r.x = c ? a.x : b.x;  r.y = c ? a.y : b.y;
    r.z = c ? a.z : b.z;  r.w = c ? a.w : b.w;
    return r;
}

__global__ __launch_bounds__(256) void spharm16_kernel(const float* __restrict__ X,
                                                       f4* __restrict__ out4,
                                                       int nf4) {
    const int t    = threadIdx.x;
    const int base = blockIdx.x * (TPB * K);          // block's first float4

#pragma unroll
    for (int j = 0; j < K; ++j) {
        const int g4 = base + j * TPB + t;            // global float4 index
        if (g4 >= nf4) return;                        // grid exact: never taken
        const int p = g4 >> 3;                        // point (8 lanes share)
        const int q = g4 & 7;                         // quad within point

        const float x = X[3 * p + 0];
        const float y = X[3 * p + 1];
        const float z = X[3 * p + 2];

        // --- angles -------------------------------------------------------
        const float r2   = x * x + y * y + z * z;
        const float rinv = rsqrtf(r2);
        const float ct   = z * rinv;
        const float ct2  = ct * ct;
        const float st2  = fmaxf(1.0f - ct2, 0.0f);
        const float st   = sqrtf(st2);

        const float rho2 = x * x + y * y;
        const float pinv = rsqrtf(rho2);
        const bool  okp  = rho2 > 0.0f;
        const float c1   = okp ? x * pinv : 1.0f;
        const float s1   = okp ? y * pinv : 0.0f;
        const float c2   = c1 * c1 - s1 * s1;
        const float s2   = 2.0f * c1 * s1;
        const float c3   = c2 * c1 - s2 * s1;
        const float s3   = s2 * c1 + c2 * s1;

        // --- normalized Legendre bases (CS phase folded into signs) -------
        const float S1  = 0.34549414947133547f * st;
        const float B10 = 0.48860251190291992f * ct;
        const float B20 = 0.63078313050504031f * (1.5f * ct2 - 0.5f);
        const float T21 = 0.77254840404637910f * ct * st;
        const float B22 = 0.38627420202318955f * st2;
        const float B30 = 0.74635266518023080f * ct * (2.5f * ct2 - 1.5f);
        const float B31 = 0.32318018411248776f * st * (1.0f - 5.0f * ct2);
        const float B32 = 1.02198547643188850f * ct * st2;
        const float T33 = 0.41722382363278404f * st2 * st;

        const float S1c1  = S1  * c1, S1s1  = S1  * s1;
        const float T21c1 = T21 * c1, T21s1 = T21 * s1;
        const float B22c2 = B22 * c2, B22s2 = B22 * s2;
        const float B31c1 = B31 * c1, B31s1 = B31 * s1;
        const float B32c2 = B32 * c2, B32s2 = B32 * s2;
        const float T33c3 = T33 * c3, T33s3 = T33 * s3;

        // --- the 8 quads of this point ------------------------------------
        const f4 q0 = mkf4(0.28209479177387814f, 0.0f,  S1c1, -S1s1);
        const f4 q1 = mkf4(B10,    0.0f,  -S1c1,  -S1s1);
        const f4 q2 = mkf4(B22c2, -B22s2,  T21c1, -T21s1);
        const f4 q3 = mkf4(B20,    0.0f,  -T21c1, -T21s1);
        const f4 q4 = mkf4(B22c2,  B22s2,  T33c3, -T33s3);
        const f4 q5 = mkf4(B32c2, -B32s2, -B31c1,  B31s1);
        const f4 q6 = mkf4(B30,    0.0f,   B31c1,  B31s1);
        const f4 q7 = mkf4(B32c2,  B32s2, -T33c3, -T33s3);

        // --- branchless 8:1 f4 mux on q -----------------------------------
        const bool b0 = (q & 1) != 0;
        const bool b1 = (q & 2) != 0;
        const bool b2 = (q & 4) != 0;
        const f4 m01 = sel4(b0, q1, q0);
        const f4 m23 = sel4(b0, q3, q2);
        const f4 m45 = sel4(b0, q5, q4);
        const f4 m67 = sel4(b0, q7, q6);
        const f4 n0  = sel4(b1, m23, m01);
        const f4 n1  = sel4(b1, m67, m45);
        const f4 res = sel4(b2, n1, n0);

        // nontemporal: write-once 64 MiB stream, skip L2 allocate/evict
        __builtin_nontemporal_store(res, &out4[g4]);
    }
}

extern "C" void kernel_launch(void* const* d_in, const int* in_sizes, int n_in,
                              void* d_out, int out_size, void* d_ws, size_t ws_size,
                              hipStream_t stream) {
    const float* X = (const float*)d_in[0];
    f4* out4 = (f4*)d_out;
    const int npts = in_sizes[0] / 3;                  // 524288
    const int nf4  = npts * 8;                         // 4194304 float4s
    const int blocks = (nf4 + TPB * K - 1) / (TPB * K);  // 2048
    spharm16_kernel<<<blocks, TPB, 0, stream>>>(X, out4, nf4);
}

// Round 14
// 76.852 us; speedup vs baseline: 1.3692x; 1.0647x over previous
//
#include <hip/hip_runtime.h>

// Spherical harmonics Y_l^m, l = 0..3, complex (re,im), packed [B,N,N,16,2] f32.
// 8 lanes per point (redundant closed-form compute), each lane stores ONE
// float4 = quad (gt&7) of point (gt>>3), selected by a branchless 7-select mux.
// No LDS, no barrier; out4[gt] is lane-consecutive -> 1 KiB contiguous per
// wave-store. REVERT of r12's nt-store+grid-stride (regressed 13.7->17.8 us:
// nt bypasses L2 write aggregation; 8-deep per-thread loop adds dep latency).
// Measured: kernel ~13.7 us (r7/r8 1x-vs-3x probe) = 5.36 TB/s mixed-stream,
// 85% of this box's pure-fill 6.3 TB/s; fixed harness window ~64 us.

constexpr int TPB = 256;

__device__ __forceinline__ float4 sel4(bool c, const float4& a, const float4& b) {
    return make_float4(c ? a.x : b.x, c ? a.y : b.y, c ? a.z : b.z, c ? a.w : b.w);
}

__global__ __launch_bounds__(256) void spharm16_kernel(const float* __restrict__ X,
                                                       float4* __restrict__ out4,
                                                       int nf4) {
    const int gt = blockIdx.x * TPB + threadIdx.x;   // global float4 index
    if (gt >= nf4) return;
    const int p = gt >> 3;                           // point (8 lanes share)
    const int q = gt & 7;                            // quad within point

    const float x = X[3 * p + 0];
    const float y = X[3 * p + 1];
    const float z = X[3 * p + 2];

    const float r2   = x * x + y * y + z * z;
    const float rinv = rsqrtf(r2);
    const float ct   = z * rinv;
    const float ct2  = ct * ct;
    const float st2  = fmaxf(1.0f - ct2, 0.0f);
    const float st   = sqrtf(st2);

    const float rho2 = x * x + y * y;
    const float pinv = rsqrtf(rho2);
    const bool  okp  = rho2 > 0.0f;
    const float c1   = okp ? x * pinv : 1.0f;
    const float s1   = okp ? y * pinv : 0.0f;
    const float c2   = c1 * c1 - s1 * s1;
    const float s2   = 2.0f * c1 * s1;
    const float c3   = c2 * c1 - s2 * s1;
    const float s3   = s2 * c1 + c2 * s1;

    const float S1  = 0.34549414947133547f * st;
    const float B10 = 0.48860251190291992f * ct;
    const float B20 = 0.63078313050504031f * (1.5f * ct2 - 0.5f);
    const float T21 = 0.77254840404637910f * ct * st;
    const float B22 = 0.38627420202318955f * st2;
    const float B30 = 0.74635266518023080f * ct * (2.5f * ct2 - 1.5f);
    const float B31 = 0.32318018411248776f * st * (1.0f - 5.0f * ct2);
    const float B32 = 1.02198547643188850f * ct * st2;
    const float T33 = 0.41722382363278404f * st2 * st;

    const float S1c1  = S1  * c1, S1s1  = S1  * s1;
    const float T21c1 = T21 * c1, T21s1 = T21 * s1;
    const float B22c2 = B22 * c2, B22s2 = B22 * s2;
    const float B31c1 = B31 * c1, B31s1 = B31 * s1;
    const float B32c2 = B32 * c2, B32s2 = B32 * s2;
    const float T33c3 = T33 * c3, T33s3 = T33 * s3;

    const float4 q0 = make_float4(0.28209479177387814f, 0.0f,  S1c1, -S1s1);
    const float4 q1 = make_float4(B10,    0.0f,  -S1c1,  -S1s1);
    const float4 q2 = make_float4(B22c2, -B22s2,  T21c1, -T21s1);
    const float4 q3 = make_float4(B20,    0.0f,  -T21c1, -T21s1);
    const float4 q4 = make_float4(B22c2,  B22s2,  T33c3, -T33s3);
    const float4 q5 = make_float4(B32c2, -B32s2, -B31c1,  B31s1);
    const float4 q6 = make_float4(B30,    0.0f,   B31c1,  B31s1);
    const float4 q7 = make_float4(B32c2,  B32s2, -T33c3, -T33s3);

    const bool b0 = (q & 1) != 0;
    const bool b1 = (q & 2) != 0;
    const bool b2 = (q & 4) != 0;
    const float4 m01 = sel4(b0, q1, q0);
    const float4 m23 = sel4(b0, q3, q2);
    const float4 m45 = sel4(b0, q5, q4);
    const float4 m67 = sel4(b0, q7, q6);
    const float4 n0  = sel4(b1, m23, m01);
    const float4 n1  = sel4(b1, m67, m45);
    const float4 res = sel4(b2, n1, n0);

    out4[gt] = res;   // lane-consecutive: 1 KiB contiguous per wave-store
}

extern "C" void kernel_launch(void* const* d_in, const int* in_sizes, int n_in,
                              void* d_out, int out_size, void* d_ws, size_t ws_size,
                              hipStream_t stream) {
    const float* X = (const float*)d_in[0];
    float4* out4 = (float4*)d_out;
    const int npts = in_sizes[0] / 3;          // 524288
    const int nf4  = npts * 8;                 // one float4 per thread
    const int blocks = (nf4 + TPB - 1) / TPB;  // 16384
    spharm16_kernel<<<blocks, TPB, 0, stream>>>(X, out4, nf4);
}